// Round 4
// baseline (95.707 us; speedup 1.0000x reference)
//
#include <hip/hip_runtime.h>
#include <math.h>

#define NS 100000
#define NC 64
#define ND 32
#define NK 576            // 18 k-tiles of 32 features
#define QBYTES (NC * NK * 2)        // 73728 B
#define NCPB 8                      // components per setup block
#define LOG2PI 1.8378770664093453f

#define MBLK 512          // main grid: exactly 2 blocks/CU on 256 CUs
#define NWAVES (MBLK * 4) // 2048 waves; unit u = 32 samples
#define NUNITS (NS / 32)  // 3125 units, 3125*32 == 100000 exactly
#define SECOND (NUNITS - NWAVES)  // waves g < 1077 run unit g+2048

typedef __attribute__((ext_vector_type(8))) __bf16 bf16x8;
typedef __attribute__((ext_vector_type(8))) float  floatx8;
typedef __attribute__((ext_vector_type(4))) float  floatx4;

// ws layout (bytes):
//   Qf  [73728 B] : Q in MFMA a-fragment order: chunk (mt*18+t)*64 + quad*16
//         + colk holds 8 bf16 (16 B) for comp mt*16+colk, feats t*32+quad*8+jj.
//   lw  [NC floats] @ 73728 : log_softmax(log_weights)
//   kc  [NC floats] @ 73984 : kconst_k - 0.5*mu^T P mu (fp32)
//
// MEASURED LESSONS:
//  - R13: TWO pairs per wave with LDS-resident Q spilled (WRITE 98.5MB,
//    main 60us): compiler CSE'd the 72 loop-invariant ds_read_b128 frags
//    across both pairs (~288 VGPRs). Fix: asm memory clobber between pairs.
//  - R9: runtime-trip-count loops also interleave -> spill. Straight-line.
//  - R5/R10: device fences + TICKET atomics cost 8-11us. Plain per-block
//    float atomicAdd is fine (R15/R16 measured: passed, absmax 0).
//  - R8: LDS-staged Q beats per-wave L2 re-read.
//  - R14: two 36KB Q-halves (4 blocks/CU) NEUTRAL: occupancy gain eaten
//    by 2x staging/barrier/fill_x/feat. More passes never wins here.
//  - R15/R16: atomic-fused reduce measured 93.19us vs 94.24 baseline with
//    fills 1.2us slower -> noise-adj -2.5us = the reduce dispatch only.
//    "gaps ~20us" (R12) is overstated; gap-removal pays ~0 beyond the
//    dispatch itself.
//  - R17 (this round): load-balance main. Old: 391 blocks -> 135 CUs at
//    4 units/SIMD, 121 CUs at 2 then idle. New: 512 blocks (exactly
//    2/CU), wave g does unit g, plus unit g+2048 iff g<1077; 3125 units
//    cover 100000 samples EXACTLY (clamps removed). Worst SIMD 4->3
//    units (-25%). Also hoist unit-1 X loads above staging+barrier so
//    HBM latency hides under the 72KB stage.

// ---------------- setup (measured ~4us steady-state) -------------------

template<int I, int Q>
__device__ __forceinline__ void load_row(const floatx4* ls4, floatx4 (&rb)[8]) {
    if constexpr (Q <= I / 4) {
        rb[Q] = ls4[I * 8 + Q];
        load_row<I, Q + 1>(ls4, rb);
    }
}

template<int I, int L>
__device__ __forceinline__ void fchain(const floatx4 (&rb)[8], const float (&a)[ND], float& s) {
    if constexpr (L < I) {
        s = fmaf(-rb[L / 4][L % 4], a[L], s);
        fchain<I, L + 1>(rb, a, s);
    }
}

template<int I>
__device__ __forceinline__ void fsub2(const floatx4* ls4, float (&a)[ND], int j) {
    if constexpr (I < ND) {
        floatx4 rb[8];
        load_row<I, 0>(ls4, rb);
        float s = (I == j) ? 1.0f : 0.0f;
        fchain<I, 0>(rb, a, s);
        float v = s / rb[I / 4][I % 4];
        a[I] = (I < j) ? 0.0f : v;
        fsub2<I + 1>(ls4, a, j);
    }
}

template<int Q>
__device__ __forceinline__ void store_ac(float* acrow, const float (&a)[ND]) {
    if constexpr (Q < 8) {
        floatx4 t;
        t[0] = a[4 * Q + 0]; t[1] = a[4 * Q + 1];
        t[2] = a[4 * Q + 2]; t[3] = a[4 * Q + 3];
        *(floatx4*)(acrow + 4 * Q) = t;
        store_ac<Q + 1>(acrow, a);
    }
}

template<int JJ>
__device__ __forceinline__ void qpack(bf16x8& v, const float* Pc, const float* bbc,
                                      int t, int quad) {
    if constexpr (JJ < 8) {
        int u = quad * 8 + JJ;
        float val;
        if (t == 0)       val = -0.5f * Pc[u * 32 + u];
        else if (t < 16)  val = -Pc[u * 32 + ((u + t) & 31)];
        else if (t == 16) val = (u < 16) ? -Pc[u * 32 + u + 16] : bbc[u - 16];
        else              val = (u < 16) ? bbc[16 + u] : 0.0f;
        v[JJ] = (__bf16)val;
        qpack<JJ + 1>(v, Pc, bbc, t, quad);
    }
}

__launch_bounds__(512)
__global__ void gmm_setup(const float* __restrict__ means,
                          const float* __restrict__ scale_tril,
                          const float* __restrict__ log_weights,
                          __bf16* __restrict__ Qf,
                          float* __restrict__ lw,
                          float* __restrict__ kc,
                          float* __restrict__ out) {
    __shared__ __align__(16) floatx4 LsP4[NCPB * 256];   // 32 KB: L, later P
    __shared__ __align__(16) float Ac[NCPB][32][36];
    __shared__ float mu_s[NCPB][32];
    __shared__ float bb_s[NCPB][32];

    const int tid  = threadIdx.x;
    const int b    = blockIdx.x;
    const int w    = tid >> 6;
    const int lane = tid & 63;

    if (b == 0 && tid == 0) out[0] = 0.0f;   // main accumulates atomically

    {
        const floatx4* g4 = (const floatx4*)scale_tril + (size_t)b * 2048;
#pragma unroll
        for (int q = 0; q < 4; ++q)
            LsP4[q * 512 + tid] = g4[q * 512 + tid];
        if (tid < NCPB * 32)
            mu_s[tid >> 5][tid & 31] = means[(size_t)(b * NCPB + (tid >> 5)) * ND + (tid & 31)];
    }
    __syncthreads();

    const floatx4* ls4 = LsP4 + w * 256;
    if (lane < ND) {
        float a[ND];
        fsub2<0>(ls4, a, lane);
        store_ac<0>(&Ac[w][lane][0], a);
    }
    float hv = (lane < ND) ? logf(((const float*)LsP4)[w * 1024 + lane * 33]) : 0.0f;
#pragma unroll
    for (int off = 1; off < 64; off <<= 1) hv += __shfl_xor(hv, off);
    float hld = hv;
    __syncthreads();

    {
        int c = tid >> 6, half = (tid >> 5) & 1, i = tid & 31;
        const floatx4* rI4 = (const floatx4*)&Ac[c][i][0];
        float* Pc = (float*)LsP4 + c * 1024;
        for (int j16 = 0; j16 < 16; ++j16) {
            int j = half * 16 + j16;
            const floatx4* rJ4 = (const floatx4*)&Ac[c][j][0];
            float s = 0.0f;
#pragma unroll
            for (int q = 0; q < 8; ++q) {
                floatx4 x = rI4[q], y = rJ4[q];
                s = fmaf(x[0], y[0], s); s = fmaf(x[1], y[1], s);
                s = fmaf(x[2], y[2], s); s = fmaf(x[3], y[3], s);
            }
            Pc[i * 32 + j] = s;
        }
    }
    __syncthreads();

    const float* Pw = (const float*)LsP4 + w * 1024;
    float bbv = 0.0f;
    if (lane < ND) {
        for (int j = 0; j < ND; ++j) bbv = fmaf(Pw[lane * 32 + j], mu_s[w][j], bbv);
        bb_s[w][lane] = bbv;
    }
    float ccv = (lane < ND) ? mu_s[w][lane] * bbv : 0.0f;
#pragma unroll
    for (int off = 1; off < 64; off <<= 1) ccv += __shfl_xor(ccv, off);
    int comp = b * NCPB + w;
    if (lane == 0)
        kc[comp] = -0.5f * ccv - 16.0f * LOG2PI - hld;

    if (b == 0 && w == 0) {
        float x = log_weights[lane];
        float mx = x;
#pragma unroll
        for (int off = 1; off < 64; off <<= 1) mx = fmaxf(mx, __shfl_xor(mx, off));
        float e = __expf(x - mx);
#pragma unroll
        for (int off = 1; off < 64; off <<= 1) e += __shfl_xor(e, off);
        lw[lane] = x - mx - logf(e);
    }

    {
        int mt = comp >> 4, colk = comp & 15;
        const float* bbc = &bb_s[w][0];
        bf16x8* qdst = (bf16x8*)Qf;
        {
            int t = lane >> 2, quad = lane & 3;
            bf16x8 v;
            qpack<0>(v, Pw, bbc, t, quad);
            qdst[(size_t)(mt * 18 + t) * 64 + quad * 16 + colk] = v;
        }
        if (lane < 8) {
            int cl2 = 64 + lane;
            int t = cl2 >> 2, quad = cl2 & 3;
            bf16x8 v;
            qpack<0>(v, Pw, bbc, t, quad);
            qdst[(size_t)(mt * 18 + t) * 64 + quad * 16 + colk] = v;
        }
    }
}

// ---------------- main ----------------

template<int G>
__device__ __forceinline__ void fill_x(const float4* p, float (&xr)[ND], int quad) {
    if constexpr (G < 8) {
        float4 v = p[(G + 2 * quad) & 7];
        xr[4 * G + 0] = v.x; xr[4 * G + 1] = v.y;
        xr[4 * G + 2] = v.z; xr[4 * G + 3] = v.w;
        fill_x<G + 1>(p, xr, quad);
    }
}

template<int T, int JJ>
__device__ __forceinline__ void feat(const float (&xr0)[ND], const float (&xr1)[ND],
                                     int quad, floatx8& f0, floatx8& f1) {
    if constexpr (JJ < 8) {
        float a0, a1, b0, b1;
        if constexpr (T < 16) {
            a0 = xr0[JJ]; b0 = xr0[(JJ + T) & 31];
            a1 = xr1[JJ]; b1 = xr1[(JJ + T) & 31];
        } else if constexpr (T == 16) {
            a0 = (quad < 2) ? xr0[JJ] : 1.0f;  b0 = xr0[(JJ + 16) & 31];
            a1 = (quad < 2) ? xr1[JJ] : 1.0f;  b1 = xr1[(JJ + 16) & 31];
        } else {
            a0 = (quad < 2) ? xr0[(JJ + 16) & 31] : 0.0f; b0 = 1.0f;
            a1 = (quad < 2) ? xr1[(JJ + 16) & 31] : 0.0f; b1 = 1.0f;
        }
        f0[JJ] = a0 * b0;
        f1[JJ] = a1 * b1;
        feat<T, JJ + 1>(xr0, xr1, quad, f0, f1);
    }
}

template<int T, int MT>
__device__ __forceinline__ void mfma_step(const unsigned char* qlane, bf16x8 b0, bf16x8 b1,
                                          floatx4 (&A0)[4], floatx4 (&A1)[4]) {
    if constexpr (MT < 4) {
        bf16x8 af = *(const bf16x8*)(qlane + (MT * 18 + T) * 1024);  // ds_read_b128
        A0[MT] = __builtin_amdgcn_mfma_f32_16x16x32_bf16(af, b0, A0[MT], 0, 0, 0);
        A1[MT] = __builtin_amdgcn_mfma_f32_16x16x32_bf16(af, b1, A1[MT], 0, 0, 0);
        mfma_step<T, MT + 1>(qlane, b0, b1, A0, A1);
    }
}

template<int T>
__device__ __forceinline__ void kloop(const unsigned char* qlane,
                                      const float (&xr0)[ND], const float (&xr1)[ND],
                                      int quad, floatx4 (&A0)[4], floatx4 (&A1)[4]) {
    if constexpr (T < 18) {
        floatx8 f0, f1;
        feat<T, 0>(xr0, xr1, quad, f0, f1);
        bf16x8 b0 = __builtin_convertvector(f0, bf16x8);
        bf16x8 b1 = __builtin_convertvector(f1, bf16x8);
        mfma_step<T, 0>(qlane, b0, b1, A0, A1);
        kloop<T + 1>(qlane, xr0, xr1, quad, A0, A1);
    }
}

template<int MT, int R>
__device__ __forceinline__ void epi_r(const floatx4 (&A0)[4], const floatx4 (&A1)[4],
                                      floatx4 lwv, floatx4 kcv,
                                      float& s0, float& w0, float& s1, float& w1) {
    if constexpr (R < 4) {
        float lp0 = A0[MT][R] + kcv[R];
        float e0 = __expf(lp0 + lwv[R]);
        s0 += e0; w0 = fmaf(e0, lp0, w0);
        float lp1 = A1[MT][R] + kcv[R];
        float e1 = __expf(lp1 + lwv[R]);
        s1 += e1; w1 = fmaf(e1, lp1, w1);
        epi_r<MT, R + 1>(A0, A1, lwv, kcv, s0, w0, s1, w1);
    }
}

template<int MT>
__device__ __forceinline__ void epi(const float* lw_s, const float* kc_s, int quad,
                                    const floatx4 (&A0)[4], const floatx4 (&A1)[4],
                                    float& s0, float& w0, float& s1, float& w1) {
    if constexpr (MT < 4) {
        floatx4 lwv = *(const floatx4*)&lw_s[MT * 16 + quad * 4];
        floatx4 kcv = *(const floatx4*)&kc_s[MT * 16 + quad * 4];
        epi_r<MT, 0>(A0, A1, lwv, kcv, s0, w0, s1, w1);
        epi<MT + 1>(lw_s, kc_s, quad, A0, A1, s0, w0, s1, w1);
    }
}

// One 32-sample unit with X already in registers. No bounds clamps: units
// exactly tile the 100000 samples.
__device__ __forceinline__ float unit_ll(const unsigned char* qlane,
                                         const float* lw_s, const float* kc_s,
                                         const float (&xr0)[ND], const float (&xr1)[ND],
                                         int quad) {
    floatx4 A0[4], A1[4];
#pragma unroll
    for (int mt = 0; mt < 4; ++mt) {
        A0[mt] = (floatx4){0.f, 0.f, 0.f, 0.f};
        A1[mt] = (floatx4){0.f, 0.f, 0.f, 0.f};
    }

    kloop<0>(qlane, xr0, xr1, quad, A0, A1);

    float s0 = 0.f, w0 = 0.f, s1 = 0.f, w1 = 0.f;
    epi<0>(lw_s, kc_s, quad, A0, A1, s0, w0, s1, w1);

    s0 += __shfl_xor(s0, 16); s0 += __shfl_xor(s0, 32);
    w0 += __shfl_xor(w0, 16); w0 += __shfl_xor(w0, 32);
    s1 += __shfl_xor(s1, 16); s1 += __shfl_xor(s1, 32);
    w1 += __shfl_xor(w1, 16); w1 += __shfl_xor(w1, 32);

    return w0 / s0 + w1 / s1;
}

// 512 blocks (exactly 2/CU), 4 waves each. Wave g = blockIdx*4+wave does
// unit g always and unit g+2048 iff g < 1077 (3125 units total, exact
// cover). Unit-1 X loads hoisted above staging+barrier to hide HBM
// latency. Clobber between units kills cross-unit CSE of LDS frags (R13).
// One plain device-scope atomicAdd per block (R15).
__launch_bounds__(256, 2)
__global__ void gmm_main(const float* __restrict__ X,
                         const __bf16* __restrict__ Qf,
                         const float* __restrict__ lw,
                         const float* __restrict__ kc,
                         float* __restrict__ out) {
    __shared__ __align__(16) unsigned char qlds[QBYTES];   // 72 KB
    __shared__ float lw_s[NC];
    __shared__ float kc_s[NC];
    __shared__ float partial[4];
    int tid = threadIdx.x;

    const int lane = tid & 63;
    const int wave = tid >> 6;
    const int quad = lane >> 4;
    const int g    = blockIdx.x * 4 + wave;

    // hoisted X loads for unit g (issue before staging; latency hides
    // under the 72KB stage + barrier)
    int n0 = g * 32 + (lane & 15);
    float xr0[ND], xr1[ND];
    fill_x<0>((const float4*)(X + (size_t)n0 * ND), xr0, quad);
    fill_x<0>((const float4*)(X + (size_t)(n0 + 16) * ND), xr1, quad);

    if (tid < NC) { lw_s[tid] = lw[tid]; kc_s[tid] = kc[tid]; }
    {
        const float4* gsrc = (const float4*)Qf;
        float4* ldst = (float4*)qlds;
#pragma unroll
        for (int i = 0; i < QBYTES / 16 / 256; ++i)
            ldst[i * 256 + tid] = gsrc[i * 256 + tid];
    }
    __syncthreads();

    const unsigned char* qlane = qlds + lane * 16;

    float ll = unit_ll(qlane, lw_s, kc_s, xr0, xr1, quad);

    if (g < SECOND) {   // wave-uniform branch: units 2048..3124
        asm volatile("" ::: "memory");   // kill cross-unit CSE (R13 spill)
        int n0b = (g + NWAVES) * 32 + (lane & 15);
        float yr0[ND], yr1[ND];
        fill_x<0>((const float4*)(X + (size_t)n0b * ND), yr0, quad);
        fill_x<0>((const float4*)(X + (size_t)(n0b + 16) * ND), yr1, quad);
        ll += unit_ll(qlane, lw_s, kc_s, yr0, yr1, quad);
    }

    // replicated across 4 quads -> butterfly gives 4x the per-wave sum
#pragma unroll
    for (int off = 1; off < 64; off <<= 1) ll += __shfl_xor(ll, off);
    if (lane == 0) partial[wave] = ll * 0.25f;
    __syncthreads();

    if (tid == 0) {
        float blk = partial[0] + partial[1] + partial[2] + partial[3];
        atomicAdd(out, blk * (-1.0f / (float)NS));
    }
}

extern "C" void kernel_launch(void* const* d_in, const int* in_sizes, int n_in,
                              void* d_out, int out_size, void* d_ws, size_t ws_size,
                              hipStream_t stream) {
    const float* X           = (const float*)d_in[0];
    const float* means       = (const float*)d_in[1];
    const float* scale_tril  = (const float*)d_in[2];
    const float* log_weights = (const float*)d_in[3];

    char* ws = (char*)d_ws;
    __bf16* Qf = (__bf16*)ws;                  // 73728 B
    float*  lw = (float*)(ws + 73728);
    float*  kc = (float*)(ws + 73984);

    gmm_setup<<<NC / NCPB, 512, 0, stream>>>(means, scale_tril, log_weights,
                                             Qf, lw, kc, (float*)d_out);
    gmm_main<<<MBLK, 256, 0, stream>>>(X, Qf, lw, kc, (float*)d_out);
}

// Round 5
// 94.207 us; speedup vs baseline: 1.0159x; 1.0159x over previous
//
#include <hip/hip_runtime.h>
#include <math.h>

#define NS 100000
#define NC 64
#define ND 32
#define NK 576            // 18 k-tiles of 32 features
#define NBLK ((NS + 255) / 256)     // 391 main blocks, 256 samples each
#define QBYTES (NC * NK * 2)        // 73728 B
#define NCPB 8                      // components per setup block
#define LOG2PI 1.8378770664093453f

typedef __attribute__((ext_vector_type(8))) __bf16 bf16x8;
typedef __attribute__((ext_vector_type(8))) float  floatx8;
typedef __attribute__((ext_vector_type(4))) float  floatx4;

// ws layout (bytes):
//   Qf  [73728 B] : Q in MFMA a-fragment order: chunk (mt*18+t)*64 + quad*16
//         + colk holds 8 bf16 (16 B) for comp mt*16+colk, feats t*32+quad*8+jj.
//   lw  [NC floats] @ 73728 : log_softmax(log_weights)
//   kc  [NC floats] @ 73984 : kconst_k - 0.5*mu^T P mu (fp32)
//
// MEASURED LESSONS:
//  - R13: TWO pairs per wave with LDS-resident Q spilled (WRITE 98.5MB,
//    main 60us): compiler CSE'd the 72 loop-invariant ds_read_b128 frags
//    across both pairs (~288 VGPRs). Fix: asm memory clobber between pairs.
//  - R9: runtime-trip-count loops also interleave -> spill. Straight-line.
//  - R5/R10: device fences + TICKET atomics cost 8-11us. Plain per-block
//    float atomicAdd is fine (R15/R16 measured: passed, absmax 0).
//  - R8: LDS-staged Q beats per-wave L2 re-read.
//  - R14: two 36KB Q-halves ("4 blocks/CU") NEUTRAL - likely VGPR-capped
//    at 2 waves/SIMD anyway; staging fixed costs ~ compute they wrap.
//  - R15/R16: atomic-fused reduce: 93.19us (best). Gap-removal pays only
//    the dispatch itself; R12's "gaps ~20us" was overstated.
//  - R17: 512-block rebalance + X-hoist REGRESSED +2.7us noise-adj.
//    Hypothesis: xr0/xr1 (64 VGPR) live across staging pushed main over
//    an occupancy threshold (waves/SIMD halve at 128/256 VGPR). Also:
//    co-resident blocks overlap stagings, so staging COUNT isn't critical
//    path - rebalancing buys nothing. REVERTED.
//  - Accounting revision (R18): serial cycle model puts main at ~5us,
//    not R12's 23; residual controllable budget (setup+main+gaps) is
//    ~9-12us. Only single-variable ~1-2us moves remain.
//  - R18 (this round): ONE change vs R15 - Q staging via
//    __builtin_amdgcn_global_load_lds width=16 (m97 pattern; dst is
//    wave-uniform base + lane*16, our layout is exactly linear).
//    Removes 18 VGPR round-trips + staging temps from the prologue.

// ---------------- setup (measured ~4us steady-state) -------------------

template<int I, int Q>
__device__ __forceinline__ void load_row(const floatx4* ls4, floatx4 (&rb)[8]) {
    if constexpr (Q <= I / 4) {
        rb[Q] = ls4[I * 8 + Q];
        load_row<I, Q + 1>(ls4, rb);
    }
}

template<int I, int L>
__device__ __forceinline__ void fchain(const floatx4 (&rb)[8], const float (&a)[ND], float& s) {
    if constexpr (L < I) {
        s = fmaf(-rb[L / 4][L % 4], a[L], s);
        fchain<I, L + 1>(rb, a, s);
    }
}

template<int I>
__device__ __forceinline__ void fsub2(const floatx4* ls4, float (&a)[ND], int j) {
    if constexpr (I < ND) {
        floatx4 rb[8];
        load_row<I, 0>(ls4, rb);
        float s = (I == j) ? 1.0f : 0.0f;
        fchain<I, 0>(rb, a, s);
        float v = s / rb[I / 4][I % 4];
        a[I] = (I < j) ? 0.0f : v;
        fsub2<I + 1>(ls4, a, j);
    }
}

template<int Q>
__device__ __forceinline__ void store_ac(float* acrow, const float (&a)[ND]) {
    if constexpr (Q < 8) {
        floatx4 t;
        t[0] = a[4 * Q + 0]; t[1] = a[4 * Q + 1];
        t[2] = a[4 * Q + 2]; t[3] = a[4 * Q + 3];
        *(floatx4*)(acrow + 4 * Q) = t;
        store_ac<Q + 1>(acrow, a);
    }
}

template<int JJ>
__device__ __forceinline__ void qpack(bf16x8& v, const float* Pc, const float* bbc,
                                      int t, int quad) {
    if constexpr (JJ < 8) {
        int u = quad * 8 + JJ;
        float val;
        if (t == 0)       val = -0.5f * Pc[u * 32 + u];
        else if (t < 16)  val = -Pc[u * 32 + ((u + t) & 31)];
        else if (t == 16) val = (u < 16) ? -Pc[u * 32 + u + 16] : bbc[u - 16];
        else              val = (u < 16) ? bbc[16 + u] : 0.0f;
        v[JJ] = (__bf16)val;
        qpack<JJ + 1>(v, Pc, bbc, t, quad);
    }
}

__launch_bounds__(512)
__global__ void gmm_setup(const float* __restrict__ means,
                          const float* __restrict__ scale_tril,
                          const float* __restrict__ log_weights,
                          __bf16* __restrict__ Qf,
                          float* __restrict__ lw,
                          float* __restrict__ kc,
                          float* __restrict__ out) {
    __shared__ __align__(16) floatx4 LsP4[NCPB * 256];   // 32 KB: L, later P
    __shared__ __align__(16) float Ac[NCPB][32][36];
    __shared__ float mu_s[NCPB][32];
    __shared__ float bb_s[NCPB][32];

    const int tid  = threadIdx.x;
    const int b    = blockIdx.x;
    const int w    = tid >> 6;
    const int lane = tid & 63;

    if (b == 0 && tid == 0) out[0] = 0.0f;   // main accumulates atomically

    {
        const floatx4* g4 = (const floatx4*)scale_tril + (size_t)b * 2048;
#pragma unroll
        for (int q = 0; q < 4; ++q)
            LsP4[q * 512 + tid] = g4[q * 512 + tid];
        if (tid < NCPB * 32)
            mu_s[tid >> 5][tid & 31] = means[(size_t)(b * NCPB + (tid >> 5)) * ND + (tid & 31)];
    }
    __syncthreads();

    const floatx4* ls4 = LsP4 + w * 256;
    if (lane < ND) {
        float a[ND];
        fsub2<0>(ls4, a, lane);
        store_ac<0>(&Ac[w][lane][0], a);
    }
    float hv = (lane < ND) ? logf(((const float*)LsP4)[w * 1024 + lane * 33]) : 0.0f;
#pragma unroll
    for (int off = 1; off < 64; off <<= 1) hv += __shfl_xor(hv, off);
    float hld = hv;
    __syncthreads();

    {
        int c = tid >> 6, half = (tid >> 5) & 1, i = tid & 31;
        const floatx4* rI4 = (const floatx4*)&Ac[c][i][0];
        float* Pc = (float*)LsP4 + c * 1024;
        for (int j16 = 0; j16 < 16; ++j16) {
            int j = half * 16 + j16;
            const floatx4* rJ4 = (const floatx4*)&Ac[c][j][0];
            float s = 0.0f;
#pragma unroll
            for (int q = 0; q < 8; ++q) {
                floatx4 x = rI4[q], y = rJ4[q];
                s = fmaf(x[0], y[0], s); s = fmaf(x[1], y[1], s);
                s = fmaf(x[2], y[2], s); s = fmaf(x[3], y[3], s);
            }
            Pc[i * 32 + j] = s;
        }
    }
    __syncthreads();

    const float* Pw = (const float*)LsP4 + w * 1024;
    float bbv = 0.0f;
    if (lane < ND) {
        for (int j = 0; j < ND; ++j) bbv = fmaf(Pw[lane * 32 + j], mu_s[w][j], bbv);
        bb_s[w][lane] = bbv;
    }
    float ccv = (lane < ND) ? mu_s[w][lane] * bbv : 0.0f;
#pragma unroll
    for (int off = 1; off < 64; off <<= 1) ccv += __shfl_xor(ccv, off);
    int comp = b * NCPB + w;
    if (lane == 0)
        kc[comp] = -0.5f * ccv - 16.0f * LOG2PI - hld;

    if (b == 0 && w == 0) {
        float x = log_weights[lane];
        float mx = x;
#pragma unroll
        for (int off = 1; off < 64; off <<= 1) mx = fmaxf(mx, __shfl_xor(mx, off));
        float e = __expf(x - mx);
#pragma unroll
        for (int off = 1; off < 64; off <<= 1) e += __shfl_xor(e, off);
        lw[lane] = x - mx - logf(e);
    }

    {
        int mt = comp >> 4, colk = comp & 15;
        const float* bbc = &bb_s[w][0];
        bf16x8* qdst = (bf16x8*)Qf;
        {
            int t = lane >> 2, quad = lane & 3;
            bf16x8 v;
            qpack<0>(v, Pw, bbc, t, quad);
            qdst[(size_t)(mt * 18 + t) * 64 + quad * 16 + colk] = v;
        }
        if (lane < 8) {
            int cl2 = 64 + lane;
            int t = cl2 >> 2, quad = cl2 & 3;
            bf16x8 v;
            qpack<0>(v, Pw, bbc, t, quad);
            qdst[(size_t)(mt * 18 + t) * 64 + quad * 16 + colk] = v;
        }
    }
}

// ---------------- main ----------------

template<int G>
__device__ __forceinline__ void fill_x(const float4* p, float (&xr)[ND], int quad) {
    if constexpr (G < 8) {
        float4 v = p[(G + 2 * quad) & 7];
        xr[4 * G + 0] = v.x; xr[4 * G + 1] = v.y;
        xr[4 * G + 2] = v.z; xr[4 * G + 3] = v.w;
        fill_x<G + 1>(p, xr, quad);
    }
}

template<int T, int JJ>
__device__ __forceinline__ void feat(const float (&xr0)[ND], const float (&xr1)[ND],
                                     int quad, floatx8& f0, floatx8& f1) {
    if constexpr (JJ < 8) {
        float a0, a1, b0, b1;
        if constexpr (T < 16) {
            a0 = xr0[JJ]; b0 = xr0[(JJ + T) & 31];
            a1 = xr1[JJ]; b1 = xr1[(JJ + T) & 31];
        } else if constexpr (T == 16) {
            a0 = (quad < 2) ? xr0[JJ] : 1.0f;  b0 = xr0[(JJ + 16) & 31];
            a1 = (quad < 2) ? xr1[JJ] : 1.0f;  b1 = xr1[(JJ + 16) & 31];
        } else {
            a0 = (quad < 2) ? xr0[(JJ + 16) & 31] : 0.0f; b0 = 1.0f;
            a1 = (quad < 2) ? xr1[(JJ + 16) & 31] : 0.0f; b1 = 1.0f;
        }
        f0[JJ] = a0 * b0;
        f1[JJ] = a1 * b1;
        feat<T, JJ + 1>(xr0, xr1, quad, f0, f1);
    }
}

template<int T, int MT>
__device__ __forceinline__ void mfma_step(const unsigned char* qlane, bf16x8 b0, bf16x8 b1,
                                          floatx4 (&A0)[4], floatx4 (&A1)[4]) {
    if constexpr (MT < 4) {
        bf16x8 af = *(const bf16x8*)(qlane + (MT * 18 + T) * 1024);  // ds_read_b128
        A0[MT] = __builtin_amdgcn_mfma_f32_16x16x32_bf16(af, b0, A0[MT], 0, 0, 0);
        A1[MT] = __builtin_amdgcn_mfma_f32_16x16x32_bf16(af, b1, A1[MT], 0, 0, 0);
        mfma_step<T, MT + 1>(qlane, b0, b1, A0, A1);
    }
}

template<int T>
__device__ __forceinline__ void kloop(const unsigned char* qlane,
                                      const float (&xr0)[ND], const float (&xr1)[ND],
                                      int quad, floatx4 (&A0)[4], floatx4 (&A1)[4]) {
    if constexpr (T < 18) {
        floatx8 f0, f1;
        feat<T, 0>(xr0, xr1, quad, f0, f1);
        bf16x8 b0 = __builtin_convertvector(f0, bf16x8);
        bf16x8 b1 = __builtin_convertvector(f1, bf16x8);
        mfma_step<T, 0>(qlane, b0, b1, A0, A1);
        kloop<T + 1>(qlane, xr0, xr1, quad, A0, A1);
    }
}

template<int MT, int R>
__device__ __forceinline__ void epi_r(const floatx4 (&A0)[4], const floatx4 (&A1)[4],
                                      floatx4 lwv, floatx4 kcv,
                                      float& s0, float& w0, float& s1, float& w1) {
    if constexpr (R < 4) {
        float lp0 = A0[MT][R] + kcv[R];
        float e0 = __expf(lp0 + lwv[R]);
        s0 += e0; w0 = fmaf(e0, lp0, w0);
        float lp1 = A1[MT][R] + kcv[R];
        float e1 = __expf(lp1 + lwv[R]);
        s1 += e1; w1 = fmaf(e1, lp1, w1);
        epi_r<MT, R + 1>(A0, A1, lwv, kcv, s0, w0, s1, w1);
    }
}

template<int MT>
__device__ __forceinline__ void epi(const float* lw_s, const float* kc_s, int quad,
                                    const floatx4 (&A0)[4], const floatx4 (&A1)[4],
                                    float& s0, float& w0, float& s1, float& w1) {
    if constexpr (MT < 4) {
        floatx4 lwv = *(const floatx4*)&lw_s[MT * 16 + quad * 4];
        floatx4 kcv = *(const floatx4*)&kc_s[MT * 16 + quad * 4];
        epi_r<MT, 0>(A0, A1, lwv, kcv, s0, w0, s1, w1);
        epi<MT + 1>(lw_s, kc_s, quad, A0, A1, s0, w0, s1, w1);
    }
}

__device__ __forceinline__ float pair_ll(const float* __restrict__ X,
                                         const unsigned char* qlane,
                                         const float* lw_s, const float* kc_s,
                                         int n0, int quad) {
    int n1 = n0 + 16;
    int n0c = n0 < NS ? n0 : NS - 1;
    int n1c = n1 < NS ? n1 : NS - 1;

    float xr0[ND], xr1[ND];
    fill_x<0>((const float4*)(X + (size_t)n0c * ND), xr0, quad);
    fill_x<0>((const float4*)(X + (size_t)n1c * ND), xr1, quad);

    floatx4 A0[4], A1[4];
#pragma unroll
    for (int mt = 0; mt < 4; ++mt) {
        A0[mt] = (floatx4){0.f, 0.f, 0.f, 0.f};
        A1[mt] = (floatx4){0.f, 0.f, 0.f, 0.f};
    }

    kloop<0>(qlane, xr0, xr1, quad, A0, A1);

    float s0 = 0.f, w0 = 0.f, s1 = 0.f, w1 = 0.f;
    epi<0>(lw_s, kc_s, quad, A0, A1, s0, w0, s1, w1);

    s0 += __shfl_xor(s0, 16); s0 += __shfl_xor(s0, 32);
    w0 += __shfl_xor(w0, 16); w0 += __shfl_xor(w0, 32);
    s1 += __shfl_xor(s1, 16); s1 += __shfl_xor(s1, 32);
    w1 += __shfl_xor(w1, 16); w1 += __shfl_xor(w1, 32);

    float ll = 0.0f;
    ll += (n0 < NS) ? (w0 / s0) : 0.0f;
    ll += (n1 < NS) ? (w1 / s1) : 0.0f;
    return ll;
}

// 256 samples per block (2 pairs per wave separated by a compiler memory
// barrier to defeat cross-pair CSE of LDS frag loads -> no spill), Q staged
// in LDS once per block via async global_load_lds (width=16, linear layout:
// dst = wave-uniform base + lane*16). One plain device-scope atomicAdd per
// block fuses the final reduction (no fences, no tickets, no reduce
// dispatch).
__launch_bounds__(256, 2)
__global__ void gmm_main(const float* __restrict__ X,
                         const __bf16* __restrict__ Qf,
                         const float* __restrict__ lw,
                         const float* __restrict__ kc,
                         float* __restrict__ out) {
    __shared__ __align__(16) unsigned char qlds[QBYTES];   // 72 KB
    __shared__ float lw_s[NC];
    __shared__ float kc_s[NC];
    __shared__ float partial[4];
    int tid = threadIdx.x;

    const int lane = tid & 63;
    const int wave = tid >> 6;
    const int quad = lane >> 4;

    if (tid < NC) { lw_s[tid] = lw[tid]; kc_s[tid] = kc[tid]; }
    {
        // async global->LDS staging: 18 x 4KB, all in flight; the
        // compiler-inserted vmcnt(0) before s_barrier is the only wait.
        const unsigned char* gsrc = (const unsigned char*)Qf;
#pragma unroll
        for (int i = 0; i < QBYTES / 4096; ++i) {
            __builtin_amdgcn_global_load_lds(
                (const __attribute__((address_space(1))) unsigned int*)
                    (gsrc + i * 4096 + tid * 16),
                (__attribute__((address_space(3))) unsigned int*)
                    (qlds + i * 4096 + wave * 1024),
                16, 0, 0);
        }
    }
    __syncthreads();

    const unsigned char* qlane = qlds + lane * 16;

    int base = blockIdx.x * 256 + wave * 32 + (lane & 15);

    float ll = pair_ll(X, qlane, lw_s, kc_s, base, quad);
    asm volatile("" ::: "memory");   // kill cross-pair CSE/interleave (R13 spill)
    ll      += pair_ll(X, qlane, lw_s, kc_s, base + 128, quad);

    // replicated across 4 quads -> butterfly gives 4x the per-wave sum
#pragma unroll
    for (int off = 1; off < 64; off <<= 1) ll += __shfl_xor(ll, off);
    if (lane == 0) partial[wave] = ll * 0.25f;
    __syncthreads();

    if (tid == 0) {
        float blk = partial[0] + partial[1] + partial[2] + partial[3];
        atomicAdd(out, blk * (-1.0f / (float)NS));
    }
}

extern "C" void kernel_launch(void* const* d_in, const int* in_sizes, int n_in,
                              void* d_out, int out_size, void* d_ws, size_t ws_size,
                              hipStream_t stream) {
    const float* X           = (const float*)d_in[0];
    const float* means       = (const float*)d_in[1];
    const float* scale_tril  = (const float*)d_in[2];
    const float* log_weights = (const float*)d_in[3];

    char* ws = (char*)d_ws;
    __bf16* Qf = (__bf16*)ws;                  // 73728 B
    float*  lw = (float*)(ws + 73728);
    float*  kc = (float*)(ws + 73984);

    gmm_setup<<<NC / NCPB, 512, 0, stream>>>(means, scale_tril, log_weights,
                                             Qf, lw, kc, (float*)d_out);
    gmm_main<<<NBLK, 256, 0, stream>>>(X, Qf, lw, kc, (float*)d_out);
}

// Round 6
// 90.793 us; speedup vs baseline: 1.0541x; 1.0376x over previous
//
#include <hip/hip_runtime.h>
#include <math.h>

#define NS 100000
#define NC 64
#define ND 32
#define NK 576            // 18 k-tiles of 32 features
#define NBLK ((NS + 255) / 256)     // 391 main blocks, 256 samples each
#define QBYTES (NC * NK * 2)        // 73728 B
#define NCPB 8                      // components per setup block
#define LOG2PI 1.8378770664093453f

typedef __attribute__((ext_vector_type(8))) __bf16 bf16x8;
typedef __attribute__((ext_vector_type(8))) float  floatx8;
typedef __attribute__((ext_vector_type(4))) float  floatx4;

// ws layout (bytes):
//   Qf  [73728 B] : Q in MFMA a-fragment order: chunk (mt*18+t)*64 + quad*16
//         + colk holds 8 bf16 (16 B) for comp mt*16+colk, feats t*32+quad*8+jj.
//   lw  [NC floats] @ 73728 : log_softmax(log_weights)
//   kc  [NC floats] @ 73984 : kconst_k - 0.5*mu^T P mu (fp32)
//
// MEASURED LESSONS:
//  - R13: two pairs/wave with cross-pair CSE of LDS frags spilled (~288
//    VGPR, main 60us). Single-pair-per-wave structure (R19) removes the
//    hazard entirely.
//  - R9: runtime-trip-count loops interleave -> spill. Straight-line.
//  - R5/R10: device fences + TICKET atomics cost 8-11us. Plain per-block
//    float atomicAdd is fine (R15/R16: passed, absmax 0).
//  - R8: LDS-staged Q beats per-wave L2 re-read.
//  - R14: two 36KB Q-halves NEUTRAL (double-pass costs ate occupancy win).
//  - R15/R16: atomic-fused reduce: 93.19us (best). Gap removal pays only
//    the dispatch itself.
//  - R17: 512-block rebalance + X-hoist REGRESSED +2.7 (VGPR-over-threshold
//    suspected). Staging count isn't critical path.
//  - R18: global_load_lds staging ~ +1us vs float4. Reverted.
//  - ACCOUNTING (R19): closing the budget against R14/R15/R17 deltas:
//    fills ~83-85 fixed, setup ~4, main ~5-8, gaps ~1-2. R12's
//    "main 23 / gaps 20" was wrong. R4's setup=42.9 rows = replay
//    artifact (contradicted by R0 top-5). Controllable budget ~10-12us.
//  - R19 (this round): main = 391 blocks x 512 threads, 8 waves x ONE
//    pair each. Same staging traffic, same 72KB LDS, but 16 waves/CU
//    (vs 8) and no second pair (no clobber needed, smaller live set).
//    __launch_bounds__(512,4) forces VGPR<=128 so 2 blocks/CU actually
//    co-reside (block granularity: 2x8 waves needs <=128). If this is
//    neutral -> occupancy is not the limiter -> at harness floor.

// ---------------- setup (~4us steady-state) -------------------

template<int I, int Q>
__device__ __forceinline__ void load_row(const floatx4* ls4, floatx4 (&rb)[8]) {
    if constexpr (Q <= I / 4) {
        rb[Q] = ls4[I * 8 + Q];
        load_row<I, Q + 1>(ls4, rb);
    }
}

template<int I, int L>
__device__ __forceinline__ void fchain(const floatx4 (&rb)[8], const float (&a)[ND], float& s) {
    if constexpr (L < I) {
        s = fmaf(-rb[L / 4][L % 4], a[L], s);
        fchain<I, L + 1>(rb, a, s);
    }
}

template<int I>
__device__ __forceinline__ void fsub2(const floatx4* ls4, float (&a)[ND], int j) {
    if constexpr (I < ND) {
        floatx4 rb[8];
        load_row<I, 0>(ls4, rb);
        float s = (I == j) ? 1.0f : 0.0f;
        fchain<I, 0>(rb, a, s);
        float v = s / rb[I / 4][I % 4];
        a[I] = (I < j) ? 0.0f : v;
        fsub2<I + 1>(ls4, a, j);
    }
}

template<int Q>
__device__ __forceinline__ void store_ac(float* acrow, const float (&a)[ND]) {
    if constexpr (Q < 8) {
        floatx4 t;
        t[0] = a[4 * Q + 0]; t[1] = a[4 * Q + 1];
        t[2] = a[4 * Q + 2]; t[3] = a[4 * Q + 3];
        *(floatx4*)(acrow + 4 * Q) = t;
        store_ac<Q + 1>(acrow, a);
    }
}

template<int JJ>
__device__ __forceinline__ void qpack(bf16x8& v, const float* Pc, const float* bbc,
                                      int t, int quad) {
    if constexpr (JJ < 8) {
        int u = quad * 8 + JJ;
        float val;
        if (t == 0)       val = -0.5f * Pc[u * 32 + u];
        else if (t < 16)  val = -Pc[u * 32 + ((u + t) & 31)];
        else if (t == 16) val = (u < 16) ? -Pc[u * 32 + u + 16] : bbc[u - 16];
        else              val = (u < 16) ? bbc[16 + u] : 0.0f;
        v[JJ] = (__bf16)val;
        qpack<JJ + 1>(v, Pc, bbc, t, quad);
    }
}

__launch_bounds__(512)
__global__ void gmm_setup(const float* __restrict__ means,
                          const float* __restrict__ scale_tril,
                          const float* __restrict__ log_weights,
                          __bf16* __restrict__ Qf,
                          float* __restrict__ lw,
                          float* __restrict__ kc,
                          float* __restrict__ out) {
    __shared__ __align__(16) floatx4 LsP4[NCPB * 256];   // 32 KB: L, later P
    __shared__ __align__(16) float Ac[NCPB][32][36];
    __shared__ float mu_s[NCPB][32];
    __shared__ float bb_s[NCPB][32];

    const int tid  = threadIdx.x;
    const int b    = blockIdx.x;
    const int w    = tid >> 6;
    const int lane = tid & 63;

    if (b == 0 && tid == 0) out[0] = 0.0f;   // main accumulates atomically

    {
        const floatx4* g4 = (const floatx4*)scale_tril + (size_t)b * 2048;
#pragma unroll
        for (int q = 0; q < 4; ++q)
            LsP4[q * 512 + tid] = g4[q * 512 + tid];
        if (tid < NCPB * 32)
            mu_s[tid >> 5][tid & 31] = means[(size_t)(b * NCPB + (tid >> 5)) * ND + (tid & 31)];
    }
    __syncthreads();

    const floatx4* ls4 = LsP4 + w * 256;
    if (lane < ND) {
        float a[ND];
        fsub2<0>(ls4, a, lane);
        store_ac<0>(&Ac[w][lane][0], a);
    }
    float hv = (lane < ND) ? logf(((const float*)LsP4)[w * 1024 + lane * 33]) : 0.0f;
#pragma unroll
    for (int off = 1; off < 64; off <<= 1) hv += __shfl_xor(hv, off);
    float hld = hv;
    __syncthreads();

    {
        int c = tid >> 6, half = (tid >> 5) & 1, i = tid & 31;
        const floatx4* rI4 = (const floatx4*)&Ac[c][i][0];
        float* Pc = (float*)LsP4 + c * 1024;
        for (int j16 = 0; j16 < 16; ++j16) {
            int j = half * 16 + j16;
            const floatx4* rJ4 = (const floatx4*)&Ac[c][j][0];
            float s = 0.0f;
#pragma unroll
            for (int q = 0; q < 8; ++q) {
                floatx4 x = rI4[q], y = rJ4[q];
                s = fmaf(x[0], y[0], s); s = fmaf(x[1], y[1], s);
                s = fmaf(x[2], y[2], s); s = fmaf(x[3], y[3], s);
            }
            Pc[i * 32 + j] = s;
        }
    }
    __syncthreads();

    const float* Pw = (const float*)LsP4 + w * 1024;
    float bbv = 0.0f;
    if (lane < ND) {
        for (int j = 0; j < ND; ++j) bbv = fmaf(Pw[lane * 32 + j], mu_s[w][j], bbv);
        bb_s[w][lane] = bbv;
    }
    float ccv = (lane < ND) ? mu_s[w][lane] * bbv : 0.0f;
#pragma unroll
    for (int off = 1; off < 64; off <<= 1) ccv += __shfl_xor(ccv, off);
    int comp = b * NCPB + w;
    if (lane == 0)
        kc[comp] = -0.5f * ccv - 16.0f * LOG2PI - hld;

    if (b == 0 && w == 0) {
        float x = log_weights[lane];
        float mx = x;
#pragma unroll
        for (int off = 1; off < 64; off <<= 1) mx = fmaxf(mx, __shfl_xor(mx, off));
        float e = __expf(x - mx);
#pragma unroll
        for (int off = 1; off < 64; off <<= 1) e += __shfl_xor(e, off);
        lw[lane] = x - mx - logf(e);
    }

    {
        int mt = comp >> 4, colk = comp & 15;
        const float* bbc = &bb_s[w][0];
        bf16x8* qdst = (bf16x8*)Qf;
        {
            int t = lane >> 2, quad = lane & 3;
            bf16x8 v;
            qpack<0>(v, Pw, bbc, t, quad);
            qdst[(size_t)(mt * 18 + t) * 64 + quad * 16 + colk] = v;
        }
        if (lane < 8) {
            int cl2 = 64 + lane;
            int t = cl2 >> 2, quad = cl2 & 3;
            bf16x8 v;
            qpack<0>(v, Pw, bbc, t, quad);
            qdst[(size_t)(mt * 18 + t) * 64 + quad * 16 + colk] = v;
        }
    }
}

// ---------------- main ----------------

template<int G>
__device__ __forceinline__ void fill_x(const float4* p, float (&xr)[ND], int quad) {
    if constexpr (G < 8) {
        float4 v = p[(G + 2 * quad) & 7];
        xr[4 * G + 0] = v.x; xr[4 * G + 1] = v.y;
        xr[4 * G + 2] = v.z; xr[4 * G + 3] = v.w;
        fill_x<G + 1>(p, xr, quad);
    }
}

template<int T, int JJ>
__device__ __forceinline__ void feat(const float (&xr0)[ND], const float (&xr1)[ND],
                                     int quad, floatx8& f0, floatx8& f1) {
    if constexpr (JJ < 8) {
        float a0, a1, b0, b1;
        if constexpr (T < 16) {
            a0 = xr0[JJ]; b0 = xr0[(JJ + T) & 31];
            a1 = xr1[JJ]; b1 = xr1[(JJ + T) & 31];
        } else if constexpr (T == 16) {
            a0 = (quad < 2) ? xr0[JJ] : 1.0f;  b0 = xr0[(JJ + 16) & 31];
            a1 = (quad < 2) ? xr1[JJ] : 1.0f;  b1 = xr1[(JJ + 16) & 31];
        } else {
            a0 = (quad < 2) ? xr0[(JJ + 16) & 31] : 0.0f; b0 = 1.0f;
            a1 = (quad < 2) ? xr1[(JJ + 16) & 31] : 0.0f; b1 = 1.0f;
        }
        f0[JJ] = a0 * b0;
        f1[JJ] = a1 * b1;
        feat<T, JJ + 1>(xr0, xr1, quad, f0, f1);
    }
}

template<int T, int MT>
__device__ __forceinline__ void mfma_step(const unsigned char* qlane, bf16x8 b0, bf16x8 b1,
                                          floatx4 (&A0)[4], floatx4 (&A1)[4]) {
    if constexpr (MT < 4) {
        bf16x8 af = *(const bf16x8*)(qlane + (MT * 18 + T) * 1024);  // ds_read_b128
        A0[MT] = __builtin_amdgcn_mfma_f32_16x16x32_bf16(af, b0, A0[MT], 0, 0, 0);
        A1[MT] = __builtin_amdgcn_mfma_f32_16x16x32_bf16(af, b1, A1[MT], 0, 0, 0);
        mfma_step<T, MT + 1>(qlane, b0, b1, A0, A1);
    }
}

template<int T>
__device__ __forceinline__ void kloop(const unsigned char* qlane,
                                      const float (&xr0)[ND], const float (&xr1)[ND],
                                      int quad, floatx4 (&A0)[4], floatx4 (&A1)[4]) {
    if constexpr (T < 18) {
        floatx8 f0, f1;
        feat<T, 0>(xr0, xr1, quad, f0, f1);
        bf16x8 b0 = __builtin_convertvector(f0, bf16x8);
        bf16x8 b1 = __builtin_convertvector(f1, bf16x8);
        mfma_step<T, 0>(qlane, b0, b1, A0, A1);
        kloop<T + 1>(qlane, xr0, xr1, quad, A0, A1);
    }
}

template<int MT, int R>
__device__ __forceinline__ void epi_r(const floatx4 (&A0)[4], const floatx4 (&A1)[4],
                                      floatx4 lwv, floatx4 kcv,
                                      float& s0, float& w0, float& s1, float& w1) {
    if constexpr (R < 4) {
        float lp0 = A0[MT][R] + kcv[R];
        float e0 = __expf(lp0 + lwv[R]);
        s0 += e0; w0 = fmaf(e0, lp0, w0);
        float lp1 = A1[MT][R] + kcv[R];
        float e1 = __expf(lp1 + lwv[R]);
        s1 += e1; w1 = fmaf(e1, lp1, w1);
        epi_r<MT, R + 1>(A0, A1, lwv, kcv, s0, w0, s1, w1);
    }
}

template<int MT>
__device__ __forceinline__ void epi(const float* lw_s, const float* kc_s, int quad,
                                    const floatx4 (&A0)[4], const floatx4 (&A1)[4],
                                    float& s0, float& w0, float& s1, float& w1) {
    if constexpr (MT < 4) {
        floatx4 lwv = *(const floatx4*)&lw_s[MT * 16 + quad * 4];
        floatx4 kcv = *(const floatx4*)&kc_s[MT * 16 + quad * 4];
        epi_r<MT, 0>(A0, A1, lwv, kcv, s0, w0, s1, w1);
        epi<MT + 1>(lw_s, kc_s, quad, A0, A1, s0, w0, s1, w1);
    }
}

__device__ __forceinline__ float pair_ll(const float* __restrict__ X,
                                         const unsigned char* qlane,
                                         const float* lw_s, const float* kc_s,
                                         int n0, int quad) {
    int n1 = n0 + 16;
    int n0c = n0 < NS ? n0 : NS - 1;
    int n1c = n1 < NS ? n1 : NS - 1;

    float xr0[ND], xr1[ND];
    fill_x<0>((const float4*)(X + (size_t)n0c * ND), xr0, quad);
    fill_x<0>((const float4*)(X + (size_t)n1c * ND), xr1, quad);

    floatx4 A0[4], A1[4];
#pragma unroll
    for (int mt = 0; mt < 4; ++mt) {
        A0[mt] = (floatx4){0.f, 0.f, 0.f, 0.f};
        A1[mt] = (floatx4){0.f, 0.f, 0.f, 0.f};
    }

    kloop<0>(qlane, xr0, xr1, quad, A0, A1);

    float s0 = 0.f, w0 = 0.f, s1 = 0.f, w1 = 0.f;
    epi<0>(lw_s, kc_s, quad, A0, A1, s0, w0, s1, w1);

    s0 += __shfl_xor(s0, 16); s0 += __shfl_xor(s0, 32);
    w0 += __shfl_xor(w0, 16); w0 += __shfl_xor(w0, 32);
    s1 += __shfl_xor(s1, 16); s1 += __shfl_xor(s1, 32);
    w1 += __shfl_xor(w1, 16); w1 += __shfl_xor(w1, 32);

    float ll = 0.0f;
    ll += (n0 < NS) ? (w0 / s0) : 0.0f;
    ll += (n1 < NS) ? (w1 / s1) : 0.0f;
    return ll;
}

// 391 blocks x 512 threads: 8 waves, ONE 32-sample pair each (256 samples
// per block, same Q-staging traffic as R15). 72KB LDS -> 2 blocks/CU ->
// 16 waves/CU; launch_bounds(512,4) forces VGPR<=128 so both blocks
// co-reside. No second pair -> no cross-pair CSE hazard, no clobber.
// One plain device-scope atomicAdd per block (R15).
__launch_bounds__(512, 4)
__global__ void gmm_main(const float* __restrict__ X,
                         const __bf16* __restrict__ Qf,
                         const float* __restrict__ lw,
                         const float* __restrict__ kc,
                         float* __restrict__ out) {
    __shared__ __align__(16) unsigned char qlds[QBYTES];   // 72 KB
    __shared__ float lw_s[NC];
    __shared__ float kc_s[NC];
    __shared__ float partial[8];
    int tid = threadIdx.x;

    if (tid < NC) { lw_s[tid] = lw[tid]; kc_s[tid] = kc[tid]; }
    {
        const float4* gsrc = (const float4*)Qf;
        float4* ldst = (float4*)qlds;
#pragma unroll
        for (int i = 0; i < QBYTES / 16 / 512; ++i)   // 9 float4 per thread
            ldst[i * 512 + tid] = gsrc[i * 512 + tid];
    }
    __syncthreads();

    const int lane = tid & 63;
    const int wave = tid >> 6;
    const int quad = lane >> 4;
    const unsigned char* qlane = qlds + lane * 16;

    int base = blockIdx.x * 256 + wave * 32 + (lane & 15);

    float ll = pair_ll(X, qlane, lw_s, kc_s, base, quad);

    // replicated across 4 quads -> butterfly gives 4x the per-wave sum
#pragma unroll
    for (int off = 1; off < 64; off <<= 1) ll += __shfl_xor(ll, off);
    if (lane == 0) partial[wave] = ll * 0.25f;
    __syncthreads();

    if (tid == 0) {
        float blk = partial[0] + partial[1] + partial[2] + partial[3]
                  + partial[4] + partial[5] + partial[6] + partial[7];
        atomicAdd(out, blk * (-1.0f / (float)NS));
    }
}

extern "C" void kernel_launch(void* const* d_in, const int* in_sizes, int n_in,
                              void* d_out, int out_size, void* d_ws, size_t ws_size,
                              hipStream_t stream) {
    const float* X           = (const float*)d_in[0];
    const float* means       = (const float*)d_in[1];
    const float* scale_tril  = (const float*)d_in[2];
    const float* log_weights = (const float*)d_in[3];

    char* ws = (char*)d_ws;
    __bf16* Qf = (__bf16*)ws;                  // 73728 B
    float*  lw = (float*)(ws + 73728);
    float*  kc = (float*)(ws + 73984);

    gmm_setup<<<NC / NCPB, 512, 0, stream>>>(means, scale_tril, log_weights,
                                             Qf, lw, kc, (float*)d_out);
    gmm_main<<<NBLK, 512, 0, stream>>>(X, Qf, lw, kc, (float*)d_out);
}